// Round 4
// baseline (2277.900 us; speedup 1.0000x reference)
//
#include <hip/hip_runtime.h>

// LSTM: B=1024, T=128, I=128, H=1024, O=64
// R5: counted-vmcnt software pipeline (T4). R4's residual stall is the
//     __syncthreads() semantics: s_waitcnt vmcnt(0) drains the just-issued
//     next-tile global_load_lds at EVERY barrier. Replace with raw
//     s_barrier + hand-counted s_waitcnt vmcnt(N):
//       prologue: stage tile0, tile1 (4 loads/wave each)
//       per tile: vmcnt(4) -> barrier -> compute -> lgkmcnt(0) -> barrier
//                 -> stage tile+2
//     Next tile's loads stay in flight across both barriers. Geometry,
//     swizzle, epilogue identical to R4 (128x128 tile, 8 waves, dbuf).

#define B_DIM 1024
#define H_DIM 1024
#define I_DIM 128
#define T_DIM 128
#define XROW  (T_DIM * I_DIM)   // 16384
#define KDIM  (I_DIM + H_DIM)   // 1152
#define GDIM  (4 * H_DIM)       // 4096
#define O_DIM 64

typedef float f32x4 __attribute__((ext_vector_type(4)));
typedef short bf16x8 __attribute__((ext_vector_type(8)));
typedef unsigned short u16x8 __attribute__((ext_vector_type(8)));

__device__ __forceinline__ unsigned short f2bf(float f) {
    union { float f; unsigned int u; } v; v.f = f;
    unsigned int r = v.u + 0x7fffu + ((v.u >> 16) & 1u);  // RNE
    return (unsigned short)(r >> 16);
}
__device__ __forceinline__ float bf2f(unsigned short b) {
    union { unsigned int u; float f; } v; v.u = ((unsigned int)b) << 16;
    return v.f;
}
__device__ __forceinline__ float sigm(float x) { return 1.f / (1.f + __expf(-x)); }
__device__ __forceinline__ float tanh_fast(float x) { return 2.f / (1.f + __expf(-2.f * x)) - 1.f; }

// ---- prep: fp32 x -> bf16 ----
__global__ void conv_x(const float* __restrict__ x, unsigned short* __restrict__ xb) {
    size_t i = ((size_t)blockIdx.x * 256 + threadIdx.x) * 8;
    float4 v0 = *(const float4*)(x + i);
    float4 v1 = *(const float4*)(x + i + 4);
    u16x8 o;
    o[0] = f2bf(v0.x); o[1] = f2bf(v0.y); o[2] = f2bf(v0.z); o[3] = f2bf(v0.w);
    o[4] = f2bf(v1.x); o[5] = f2bf(v1.y); o[6] = f2bf(v1.z); o[7] = f2bf(v1.w);
    *(u16x8*)(xb + i) = o;
}

// ---- prep: gate-interleaved W'' [4096 x 1152] bf16 + combined bias ----
__global__ void build_w(const float* __restrict__ w_ih, const float* __restrict__ w_hh,
                        const float* __restrict__ b_ih, const float* __restrict__ b_hh,
                        unsigned short* __restrict__ W, float* __restrict__ bias) {
    int r = blockIdx.x;
    int nb = r >> 7, q = r & 127;
    int wh = q >> 6, w = q & 63;
    int gate = w >> 4, jl = w & 15;
    int orig = gate * 1024 + nb * 32 + wh * 16 + jl;
    for (int k = threadIdx.x; k < KDIM; k += 256) {
        float v = (k < I_DIM) ? w_ih[(size_t)orig * I_DIM + k]
                              : w_hh[(size_t)orig * H_DIM + (k - I_DIM)];
        W[(size_t)r * KDIM + k] = f2bf(v);
    }
    if (threadIdx.x == 0) bias[r] = b_ih[orig] + b_hh[orig];
}

// ---- prep: transpose w_fc [O][H] -> wT [H][O] so proj loads coalesce ----
__global__ void trans_wfc(const float* __restrict__ w_fc, float* __restrict__ wT) {
    int o = blockIdx.x;
    for (int k = threadIdx.x; k < H_DIM; k += 256)
        wT[(size_t)k * O_DIM + o] = w_fc[(size_t)o * H_DIM + k];
}

__global__ void zero_hc(unsigned short* __restrict__ h0, float* __restrict__ c) {
    int idx = blockIdx.x * 256 + threadIdx.x;
    h0[idx] = 0;
    c[idx] = 0.f;
}

// ---- per-timestep: 128x128 tile GEMM + fused LSTM cell epilogue ----
// 8 waves in 4x2 grid; per wave 32x64 output, acc[2][4] with ni == gate.
// LDS XOR-swizzled. Counted-vmcnt double-buffer (see header comment).
// Grid 256 = 1 block/CU; XCD x owns nb in [4x,4x+4) (W slices L2-resident).
__global__ __launch_bounds__(512, 2)
void lstm_step(const unsigned short* __restrict__ xb,
               const unsigned short* __restrict__ W,
               const float* __restrict__ bias,
               const unsigned short* __restrict__ h_in,
               unsigned short* __restrict__ h_out,
               float* __restrict__ c_st,
               int t) {
    __shared__ __align__(16) unsigned short As0[128 * 64];
    __shared__ __align__(16) unsigned short Bs0[128 * 64];
    __shared__ __align__(16) unsigned short As1[128 * 64];
    __shared__ __align__(16) unsigned short Bs1[128 * 64];
    const int tid  = threadIdx.x;
    const int wv   = tid >> 6, lane = tid & 63;
    const int wm   = wv >> 1, wn = wv & 1;      // 4x2 wave grid over 128x128
    const int quad = lane >> 4, l16 = lane & 15;
    const int l7   = l16 & 7;
    const int bid = blockIdx.x;
    const int xcd = bid & 7;
    const int sl  = bid >> 3;            // 0..31
    const int nb  = xcd * 4 + (sl & 3);  // 0..31 : XCD x owns nb in [4x,4x+4)
    const int mb  = sl >> 2;             // 0..7

    // epilogue addressing + prefetch of bias and old cell state
    const int j  = nb * 32 + wn * 16 + l16;
    const int bb = nb * 128 + wn * 64 + l16;
    const float bi  = bias[bb +  0];
    const float bf_ = bias[bb + 16];
    const float bg  = bias[bb + 32];
    const float bo  = bias[bb + 48];
    float cold[2][4];
#pragma unroll
    for (int mi = 0; mi < 2; mi++)
#pragma unroll
        for (int r = 0; r < 4; r++) {
            const int brow = mb * 128 + wm * 32 + mi * 16 + quad * 4 + r;
            cold[mi][r] = c_st[(size_t)brow * H_DIM + j];
        }

    f32x4 acc[2][4];
#pragma unroll
    for (int i = 0; i < 2; i++)
#pragma unroll
        for (int jj = 0; jj < 4; jj++) acc[i][jj] = f32x4{0.f, 0.f, 0.f, 0.f};

    const int arow = lane >> 3;              // 0..7: row within 8-row chunk
    const int ag   = lane & 7;               // physical 16B group this lane fills
    const int colperm = ((ag ^ arow) << 3);  // swizzled source column (bf16 units)

    // stage one 64-wide K-tile: exactly 4 global_load_lds per WAVE
    // (2 A-chunks + 2 B-chunks) -- uniform count is what makes the
    // vmcnt(N) protocol valid.
    auto stage = [&](unsigned short (&As_)[128 * 64],
                     unsigned short (&Bs_)[128 * 64], int ks) {
        const int kt = ks * 64;
#pragma unroll
        for (int c4 = 0; c4 < 2; ++c4) {
            const int row0 = wv * 16 + c4 * 8;
            const int row  = row0 + arow;
            const unsigned short* srcA =
                (kt < I_DIM)
                    ? xb   + (size_t)(mb * 128 + row) * XROW + t * I_DIM + kt + colperm
                    : h_in + (size_t)(mb * 128 + row) * H_DIM + (kt - I_DIM) + colperm;
            __builtin_amdgcn_global_load_lds(
                (const __attribute__((address_space(1))) void*)srcA,
                (__attribute__((address_space(3))) void*)(&As_[row0 * 64]), 16, 0, 0);
        }
#pragma unroll
        for (int c4 = 0; c4 < 2; ++c4) {
            const int row0 = wv * 16 + c4 * 8;
            const int row  = row0 + arow;
            const unsigned short* srcB =
                W + (size_t)(nb * 128 + row) * KDIM + kt + colperm;
            __builtin_amdgcn_global_load_lds(
                (const __attribute__((address_space(1))) void*)srcB,
                (__attribute__((address_space(3))) void*)(&Bs_[row0 * 64]), 16, 0, 0);
        }
    };

    auto compute = [&](const unsigned short (&As_)[128 * 64],
                       const unsigned short (&Bs_)[128 * 64]) {
#pragma unroll
        for (int kk = 0; kk < 64; kk += 32) {
            const int gb = kk >> 3;  // logical group base: 0 or 4
            bf16x8 af[2], bfr[4];
#pragma unroll
            for (int mi = 0; mi < 2; mi++) {
                const int r = wm * 32 + mi * 16 + l16;
                af[mi] = *(const bf16x8*)&As_[r * 64 + (((gb + quad) ^ l7) << 3)];
            }
#pragma unroll
            for (int ni = 0; ni < 4; ni++) {
                const int r = wn * 64 + ni * 16 + l16;
                bfr[ni] = *(const bf16x8*)&Bs_[r * 64 + (((gb + quad) ^ l7) << 3)];
            }
#pragma unroll
            for (int mi = 0; mi < 2; mi++)
#pragma unroll
                for (int ni = 0; ni < 4; ni++)
                    acc[mi][ni] = __builtin_amdgcn_mfma_f32_16x16x32_bf16(
                        af[mi], bfr[ni], acc[mi][ni], 0, 0, 0);
        }
    };

    // ---- counted-vmcnt pipeline: 2 tiles in flight, 4 loads/wave/tile ----
    stage(As0, Bs0, 0);
    stage(As1, Bs1, 1);
#pragma unroll 1
    for (int it = 0; it < 8; ++it) {
        // tile 2it (in As0/Bs0): oldest 4 loads must be retired
        asm volatile("s_waitcnt vmcnt(4)" ::: "memory");
        __builtin_amdgcn_s_barrier();            // all waves' tile-2it loads landed
        compute(As0, Bs0);
        asm volatile("s_waitcnt lgkmcnt(0)" ::: "memory");  // my ds_reads executed
        __builtin_amdgcn_s_barrier();            // nobody still reading As0/Bs0
        stage(As0, Bs0, 2 * it + 2);             // tile <= 16

        // tile 2it+1 (in As1/Bs1)
        asm volatile("s_waitcnt vmcnt(4)" ::: "memory");
        __builtin_amdgcn_s_barrier();
        compute(As1, Bs1);
        asm volatile("s_waitcnt lgkmcnt(0)" ::: "memory");
        __builtin_amdgcn_s_barrier();
        stage(As1, Bs1, 2 * it + 3);             // tile <= 17
    }
    // tail: tiles 16 (As0/Bs0) and 17 (As1/Bs1) staged, no more staging
    asm volatile("s_waitcnt vmcnt(4)" ::: "memory");
    __builtin_amdgcn_s_barrier();
    compute(As0, Bs0);                           // tile 16
    asm volatile("s_waitcnt vmcnt(0)" ::: "memory");
    __builtin_amdgcn_s_barrier();
    compute(As1, Bs1);                           // tile 17

    // epilogue: ni == gate (0:i 1:f 2:g 3:o), fully in-lane
#pragma unroll
    for (int mi = 0; mi < 2; mi++) {
#pragma unroll
        for (int r = 0; r < 4; r++) {
            const int brow = mb * 128 + wm * 32 + mi * 16 + quad * 4 + r;
            const float gi = acc[mi][0][r] + bi;
            const float gf = acc[mi][1][r] + bf_;
            const float gg = acc[mi][2][r] + bg;
            const float go = acc[mi][3][r] + bo;
            const size_t idx = (size_t)brow * H_DIM + j;
            const float cn = sigm(gf) * cold[mi][r] + sigm(gi) * tanh_fast(gg);
            c_st[idx] = cn;
            h_out[idx] = f2bf(sigm(go) * tanh_fast(cn));
        }
    }
}

// ---- final projection: 4 batch rows per block, lane = output dim ----
__global__ void proj(const unsigned short* __restrict__ h,
                     const float* __restrict__ wT,
                     const float* __restrict__ b_fc,
                     float* __restrict__ out) {
    __shared__ float hs[4][H_DIM];
    const int tid = threadIdx.x, wv = tid >> 6, o = tid & 63;
    const int b = blockIdx.x * 4 + wv;
    const unsigned short* hrow = h + (size_t)b * H_DIM;
#pragma unroll
    for (int i = 0; i < 2; ++i) {
        const int k0 = i * 512 + o * 8;
        u16x8 v = *(const u16x8*)(hrow + k0);
        float4 f0 = {bf2f((unsigned short)v[0]), bf2f((unsigned short)v[1]),
                     bf2f((unsigned short)v[2]), bf2f((unsigned short)v[3])};
        float4 f1 = {bf2f((unsigned short)v[4]), bf2f((unsigned short)v[5]),
                     bf2f((unsigned short)v[6]), bf2f((unsigned short)v[7])};
        *(float4*)&hs[wv][k0]     = f0;
        *(float4*)&hs[wv][k0 + 4] = f1;
    }
    float s0 = 0.f, s1 = 0.f, s2 = 0.f, s3 = 0.f;
#pragma unroll 4
    for (int k4 = 0; k4 < H_DIM / 4; ++k4) {
        float4 hv = *(const float4*)&hs[wv][k4 * 4];
        const float* wp = wT + (size_t)k4 * 4 * O_DIM + o;
        s0 += hv.x * wp[0 * O_DIM];
        s1 += hv.y * wp[1 * O_DIM];
        s2 += hv.z * wp[2 * O_DIM];
        s3 += hv.w * wp[3 * O_DIM];
    }
    out[(size_t)b * O_DIM + o] = s0 + s1 + s2 + s3 + b_fc[o];
}

extern "C" void kernel_launch(void* const* d_in, const int* in_sizes, int n_in,
                              void* d_out, int out_size, void* d_ws, size_t ws_size,
                              hipStream_t stream) {
    const float* x    = (const float*)d_in[0];
    const float* w_ih = (const float*)d_in[1];
    const float* w_hh = (const float*)d_in[2];
    const float* b_ih = (const float*)d_in[3];
    const float* b_hh = (const float*)d_in[4];
    const float* w_fc = (const float*)d_in[5];
    const float* b_fc = (const float*)d_in[6];
    float* out = (float*)d_out;

    char* ws = (char*)d_ws;
    size_t off = 0;
    unsigned short* xb = (unsigned short*)(ws + off); off += (size_t)B_DIM * XROW * 2;
    unsigned short* W  = (unsigned short*)(ws + off); off += (size_t)GDIM * KDIM * 2;
    float* bias        = (float*)(ws + off);          off += (size_t)GDIM * 4;
    unsigned short* h0 = (unsigned short*)(ws + off); off += (size_t)B_DIM * H_DIM * 2;
    unsigned short* h1 = (unsigned short*)(ws + off); off += (size_t)B_DIM * H_DIM * 2;
    float* c           = (float*)(ws + off);          off += (size_t)B_DIM * H_DIM * 4;
    float* wT          = (float*)(ws + off);          off += (size_t)H_DIM * O_DIM * 4;

    conv_x<<<8192, 256, 0, stream>>>(x, xb);
    build_w<<<GDIM, 256, 0, stream>>>(w_ih, w_hh, b_ih, b_hh, W, bias);
    trans_wfc<<<O_DIM, 256, 0, stream>>>(w_fc, wT);
    zero_hc<<<4096, 256, 0, stream>>>(h0, c);

    for (int t = 0; t < T_DIM; ++t) {
        const unsigned short* hin = (t & 1) ? h1 : h0;
        unsigned short* hout      = (t & 1) ? h0 : h1;
        lstm_step<<<256, 512, 0, stream>>>(xb, W, bias, hin, hout, c, t);
    }
    // t=127 wrote h0
    proj<<<256, 256, 0, stream>>>(h0, wT, b_fc, out);
}

// Round 6
// 1976.274 us; speedup vs baseline: 1.1526x; 1.1526x over previous
//
#include <hip/hip_runtime.h>

// LSTM: B=1024, T=128, I=128, H=1024, O=64
// R7: R6 resubmit, hardened codegen (R6: container failed, no counters —
//     infra vs kernel undetermined; protocol has no deadlock mechanism).
//     Changes vs R6: single __shared__ array with compile-time buffer
//     offsets (one ptrtoint; buf1 via ds_read offset:32768 immediate),
//     named fragment vars as asm outputs (no local array), runtime-bsel
//     staging (legal now that all LDS reads are inline asm).
//     Mechanism under test: asm ds_read_b128 is invisible to
//     SIInsertWaitcnts, so the hand-counted vmcnt(4) is the ONLY DMA wait
//     -> next tile's global_load_lds stays in flight under compute
//     (R4/R5: compiler's own vmcnt(0) before its ds_reads serialized every
//     tile at ~16.6us/step).

#define B_DIM 1024
#define H_DIM 1024
#define I_DIM 128
#define T_DIM 128
#define XROW  (T_DIM * I_DIM)   // 16384
#define KDIM  (I_DIM + H_DIM)   // 1152
#define GDIM  (4 * H_DIM)       // 4096
#define O_DIM 64

typedef float f32x4 __attribute__((ext_vector_type(4)));
typedef short bf16x8 __attribute__((ext_vector_type(8)));
typedef unsigned short u16x8 __attribute__((ext_vector_type(8)));

__device__ __forceinline__ unsigned short f2bf(float f) {
    union { float f; unsigned int u; } v; v.f = f;
    unsigned int r = v.u + 0x7fffu + ((v.u >> 16) & 1u);  // RNE
    return (unsigned short)(r >> 16);
}
__device__ __forceinline__ float bf2f(unsigned short b) {
    union { unsigned int u; float f; } v; v.u = ((unsigned int)b) << 16;
    return v.f;
}
__device__ __forceinline__ float sigm(float x) { return 1.f / (1.f + __expf(-x)); }
__device__ __forceinline__ float tanh_fast(float x) { return 2.f / (1.f + __expf(-2.f * x)) - 1.f; }

// ---- prep: fp32 x -> bf16 ----
__global__ void conv_x(const float* __restrict__ x, unsigned short* __restrict__ xb) {
    size_t i = ((size_t)blockIdx.x * 256 + threadIdx.x) * 8;
    float4 v0 = *(const float4*)(x + i);
    float4 v1 = *(const float4*)(x + i + 4);
    u16x8 o;
    o[0] = f2bf(v0.x); o[1] = f2bf(v0.y); o[2] = f2bf(v0.z); o[3] = f2bf(v0.w);
    o[4] = f2bf(v1.x); o[5] = f2bf(v1.y); o[6] = f2bf(v1.z); o[7] = f2bf(v1.w);
    *(u16x8*)(xb + i) = o;
}

// ---- prep: gate-interleaved W'' [4096 x 1152] bf16 + combined bias ----
__global__ void build_w(const float* __restrict__ w_ih, const float* __restrict__ w_hh,
                        const float* __restrict__ b_ih, const float* __restrict__ b_hh,
                        unsigned short* __restrict__ W, float* __restrict__ bias) {
    int r = blockIdx.x;
    int nb = r >> 7, q = r & 127;
    int wh = q >> 6, w = q & 63;
    int gate = w >> 4, jl = w & 15;
    int orig = gate * 1024 + nb * 32 + wh * 16 + jl;
    for (int k = threadIdx.x; k < KDIM; k += 256) {
        float v = (k < I_DIM) ? w_ih[(size_t)orig * I_DIM + k]
                              : w_hh[(size_t)orig * H_DIM + (k - I_DIM)];
        W[(size_t)r * KDIM + k] = f2bf(v);
    }
    if (threadIdx.x == 0) bias[r] = b_ih[orig] + b_hh[orig];
}

// ---- prep: transpose w_fc [O][H] -> wT [H][O] so proj loads coalesce ----
__global__ void trans_wfc(const float* __restrict__ w_fc, float* __restrict__ wT) {
    int o = blockIdx.x;
    for (int k = threadIdx.x; k < H_DIM; k += 256)
        wT[(size_t)k * O_DIM + o] = w_fc[(size_t)o * H_DIM + k];
}

__global__ void zero_hc(unsigned short* __restrict__ h0, float* __restrict__ c) {
    int idx = blockIdx.x * 256 + threadIdx.x;
    h0[idx] = 0;
    c[idx] = 0.f;
}

// 12 ds_read_b128 for one K-tile. OFF selects buffer (0 / 32768 bytes).
// kk=32 fragments are addr^64 (== swizzled col (x^4)<<4 for x<8).
#define READ_TILE(OFF) do {                                                       \
    asm volatile("ds_read_b128 %0, %1 offset:" OFF : "=v"(fa0) : "v"(aA0));       \
    asm volatile("ds_read_b128 %0, %1 offset:" OFF : "=v"(fa1) : "v"(aA1));       \
    asm volatile("ds_read_b128 %0, %1 offset:" OFF : "=v"(fb0) : "v"(aB0));       \
    asm volatile("ds_read_b128 %0, %1 offset:" OFF : "=v"(fb1) : "v"(aB1));       \
    asm volatile("ds_read_b128 %0, %1 offset:" OFF : "=v"(fb2) : "v"(aB2));       \
    asm volatile("ds_read_b128 %0, %1 offset:" OFF : "=v"(fb3) : "v"(aB3));       \
    asm volatile("ds_read_b128 %0, %1 offset:" OFF : "=v"(ga0) : "v"(aA0x));      \
    asm volatile("ds_read_b128 %0, %1 offset:" OFF : "=v"(ga1) : "v"(aA1x));      \
    asm volatile("ds_read_b128 %0, %1 offset:" OFF : "=v"(gb0) : "v"(aB0x));      \
    asm volatile("ds_read_b128 %0, %1 offset:" OFF : "=v"(gb1) : "v"(aB1x));      \
    asm volatile("ds_read_b128 %0, %1 offset:" OFF : "=v"(gb2) : "v"(aB2x));      \
    asm volatile("ds_read_b128 %0, %1 offset:" OFF : "=v"(gb3) : "v"(aB3x));      \
    asm volatile("s_waitcnt lgkmcnt(0)" ::: "memory");                            \
    __builtin_amdgcn_sched_barrier(0);                                            \
} while (0)

#define MFMA_(a, b, c) c = __builtin_amdgcn_mfma_f32_16x16x32_bf16(a, b, c, 0, 0, 0)
#define MM_TILE() do {                                                            \
    MFMA_(fa0, fb0, acc[0][0]); MFMA_(fa0, fb1, acc[0][1]);                       \
    MFMA_(fa0, fb2, acc[0][2]); MFMA_(fa0, fb3, acc[0][3]);                       \
    MFMA_(fa1, fb0, acc[1][0]); MFMA_(fa1, fb1, acc[1][1]);                       \
    MFMA_(fa1, fb2, acc[1][2]); MFMA_(fa1, fb3, acc[1][3]);                       \
    MFMA_(ga0, gb0, acc[0][0]); MFMA_(ga0, gb1, acc[0][1]);                       \
    MFMA_(ga0, gb2, acc[0][2]); MFMA_(ga0, gb3, acc[0][3]);                       \
    MFMA_(ga1, gb0, acc[1][0]); MFMA_(ga1, gb1, acc[1][1]);                       \
    MFMA_(ga1, gb2, acc[1][2]); MFMA_(ga1, gb3, acc[1][3]);                       \
} while (0)

// ---- per-timestep: 128x128 tile GEMM + fused LSTM cell epilogue ----
__global__ __launch_bounds__(512, 2)
void lstm_step(const unsigned short* __restrict__ xb,
               const unsigned short* __restrict__ W,
               const float* __restrict__ bias,
               const unsigned short* __restrict__ h_in,
               unsigned short* __restrict__ h_out,
               float* __restrict__ c_st,
               int t) {
    // layout (elements): As0[8192] | Bs0[8192] | As1[8192] | Bs1[8192]
    // byte offsets:         0      |  16384    |  32768    |  49152
    __shared__ __align__(16) unsigned short lds[4 * 8192];
    const int tid  = threadIdx.x;
    const int wv   = tid >> 6, lane = tid & 63;
    const int wm   = wv >> 1, wn = wv & 1;      // 4x2 wave grid over 128x128
    const int quad = lane >> 4, l16 = lane & 15;
    const int l7   = l16 & 7;
    const int bid = blockIdx.x;
    const int xcd = bid & 7;
    const int sl  = bid >> 3;            // 0..31
    const int nb  = xcd * 4 + (sl & 3);  // 0..31 : XCD x owns nb in [4x,4x+4)
    const int mb  = sl >> 2;             // 0..7

    // epilogue addressing + prefetch of bias and old cell state
    const int j  = nb * 32 + wn * 16 + l16;
    const int bb = nb * 128 + wn * 64 + l16;
    const float bi  = bias[bb +  0];
    const float bf_ = bias[bb + 16];
    const float bg  = bias[bb + 32];
    const float bo  = bias[bb + 48];
    float cold[2][4];
#pragma unroll
    for (int mi = 0; mi < 2; mi++)
#pragma unroll
        for (int r = 0; r < 4; r++) {
            const int brow = mb * 128 + wm * 32 + mi * 16 + quad * 4 + r;
            cold[mi][r] = c_st[(size_t)brow * H_DIM + j];
        }

    f32x4 acc[2][4];
#pragma unroll
    for (int i = 0; i < 2; i++)
#pragma unroll
        for (int jj = 0; jj < 4; jj++) acc[i][jj] = f32x4{0.f, 0.f, 0.f, 0.f};

    const int arow = lane >> 3;              // 0..7: row within 8-row chunk
    const int ag   = lane & 7;               // physical 16B group this lane fills
    const int colperm = ((ag ^ arow) << 3);  // swizzled source column (bf16 units)

    // stage one 64-wide K-tile into buffer bsel: exactly 4 DMA loads/wave
    auto stage = [&](int bsel, int ks) {
        const int kt = ks * 64;
        unsigned short* As_ = lds + bsel * 16384;   // +32768 bytes for bsel=1
        unsigned short* Bs_ = As_ + 8192;
#pragma unroll
        for (int c4 = 0; c4 < 2; ++c4) {
            const int row0 = wv * 16 + c4 * 8;
            const int row  = row0 + arow;
            const unsigned short* srcA =
                (kt < I_DIM)
                    ? xb   + (size_t)(mb * 128 + row) * XROW + t * I_DIM + kt + colperm
                    : h_in + (size_t)(mb * 128 + row) * H_DIM + (kt - I_DIM) + colperm;
            __builtin_amdgcn_global_load_lds(
                (const __attribute__((address_space(1))) void*)srcA,
                (__attribute__((address_space(3))) void*)(&As_[row0 * 64]), 16, 0, 0);
        }
#pragma unroll
        for (int c4 = 0; c4 < 2; ++c4) {
            const int row0 = wv * 16 + c4 * 8;
            const int row  = row0 + arow;
            const unsigned short* srcB =
                W + (size_t)(nb * 128 + row) * KDIM + kt + colperm;
            __builtin_amdgcn_global_load_lds(
                (const __attribute__((address_space(1))) void*)srcB,
                (__attribute__((address_space(3))) void*)(&Bs_[row0 * 64]), 16, 0, 0);
        }
    };

    // asm ds_read addresses (bytes). Row stride 128 B; frag col = (quad^l7)<<4.
    const unsigned lbase = (unsigned)(unsigned long long)
        (__attribute__((address_space(3))) void*)lds;
    const unsigned cp  = (unsigned)((quad ^ l7) << 4);
    const unsigned aA0 = lbase + (unsigned)((wm * 32 + l16) * 128) + cp;
    const unsigned aA1 = aA0 + 2048;                 // +16 rows
    const unsigned aB0 = lbase + 16384u + (unsigned)((wn * 64 + l16) * 128) + cp;
    const unsigned aB1 = aB0 + 2048;
    const unsigned aB2 = aB0 + 4096;
    const unsigned aB3 = aB0 + 6144;
    const unsigned aA0x = aA0 ^ 64u, aA1x = aA1 ^ 64u;
    const unsigned aB0x = aB0 ^ 64u, aB1x = aB1 ^ 64u;
    const unsigned aB2x = aB2 ^ 64u, aB3x = aB3 ^ 64u;
    bf16x8 fa0, fa1, fb0, fb1, fb2, fb3, ga0, ga1, gb0, gb1, gb2, gb3;

    // ---- counted-vmcnt pipeline: 2 tiles in flight, 4 DMA loads/wave/tile ----
    stage(0, 0);
    stage(1, 1);
#pragma unroll 1
    for (int p = 0; p < 8; ++p) {
        // tile 2p in buf0: my oldest 4 loads retired + barrier => buf0 ready
        asm volatile("s_waitcnt vmcnt(4)" ::: "memory");
        __builtin_amdgcn_s_barrier();
        READ_TILE("0");                      // frags in regs, lgkmcnt(0) done
        __builtin_amdgcn_s_barrier();        // all waves done reading buf0
        stage(0, 2 * p + 2);                 // overwrite buf0 (DMA in flight)
        MM_TILE();                           // compute under DMA

        // tile 2p+1 in buf1
        asm volatile("s_waitcnt vmcnt(4)" ::: "memory");
        __builtin_amdgcn_s_barrier();
        READ_TILE("32768");
        __builtin_amdgcn_s_barrier();
        stage(1, 2 * p + 3);
        MM_TILE();
    }
    // tail: tiles 16 (buf0) and 17 (buf1) staged, no more staging
    asm volatile("s_waitcnt vmcnt(4)" ::: "memory");
    __builtin_amdgcn_s_barrier();
    READ_TILE("0");
    MM_TILE();
    asm volatile("s_waitcnt vmcnt(0)" ::: "memory");
    __builtin_amdgcn_s_barrier();
    READ_TILE("32768");
    MM_TILE();

    // epilogue: ni == gate (0:i 1:f 2:g 3:o), fully in-lane
#pragma unroll
    for (int mi = 0; mi < 2; mi++) {
#pragma unroll
        for (int r = 0; r < 4; r++) {
            const int brow = mb * 128 + wm * 32 + mi * 16 + quad * 4 + r;
            const float gi = acc[mi][0][r] + bi;
            const float gf = acc[mi][1][r] + bf_;
            const float gg = acc[mi][2][r] + bg;
            const float go = acc[mi][3][r] + bo;
            const size_t idx = (size_t)brow * H_DIM + j;
            const float cn = sigm(gf) * cold[mi][r] + sigm(gi) * tanh_fast(gg);
            c_st[idx] = cn;
            h_out[idx] = f2bf(sigm(go) * tanh_fast(cn));
        }
    }
}

// ---- final projection: 4 batch rows per block, lane = output dim ----
__global__ void proj(const unsigned short* __restrict__ h,
                     const float* __restrict__ wT,
                     const float* __restrict__ b_fc,
                     float* __restrict__ out) {
    __shared__ float hs[4][H_DIM];
    const int tid = threadIdx.x, wv = tid >> 6, o = tid & 63;
    const int b = blockIdx.x * 4 + wv;
    const unsigned short* hrow = h + (size_t)b * H_DIM;
#pragma unroll
    for (int i = 0; i < 2; ++i) {
        const int k0 = i * 512 + o * 8;
        u16x8 v = *(const u16x8*)(hrow + k0);
        float4 f0 = {bf2f((unsigned short)v[0]), bf2f((unsigned short)v[1]),
                     bf2f((unsigned short)v[2]), bf2f((unsigned short)v[3])};
        float4 f1 = {bf2f((unsigned short)v[4]), bf2f((unsigned short)v[5]),
                     bf2f((unsigned short)v[6]), bf2f((unsigned short)v[7])};
        *(float4*)&hs[wv][k0]     = f0;
        *(float4*)&hs[wv][k0 + 4] = f1;
    }
    float s0 = 0.f, s1 = 0.f, s2 = 0.f, s3 = 0.f;
#pragma unroll 4
    for (int k4 = 0; k4 < H_DIM / 4; ++k4) {
        float4 hv = *(const float4*)&hs[wv][k4 * 4];
        const float* wp = wT + (size_t)k4 * 4 * O_DIM + o;
        s0 += hv.x * wp[0 * O_DIM];
        s1 += hv.y * wp[1 * O_DIM];
        s2 += hv.z * wp[2 * O_DIM];
        s3 += hv.w * wp[3 * O_DIM];
    }
    out[(size_t)b * O_DIM + o] = s0 + s1 + s2 + s3 + b_fc[o];
}

extern "C" void kernel_launch(void* const* d_in, const int* in_sizes, int n_in,
                              void* d_out, int out_size, void* d_ws, size_t ws_size,
                              hipStream_t stream) {
    const float* x    = (const float*)d_in[0];
    const float* w_ih = (const float*)d_in[1];
    const float* w_hh = (const float*)d_in[2];
    const float* b_ih = (const float*)d_in[3];
    const float* b_hh = (const float*)d_in[4];
    const float* w_fc = (const float*)d_in[5];
    const float* b_fc = (const float*)d_in[6];
    float* out = (float*)d_out;

    char* ws = (char*)d_ws;
    size_t off = 0;
    unsigned short* xb = (unsigned short*)(ws + off); off += (size_t)B_DIM * XROW * 2;
    unsigned short* W  = (unsigned short*)(ws + off); off += (size_t)GDIM * KDIM * 2;
    float* bias        = (float*)(ws + off);          off += (size_t)GDIM * 4;
    unsigned short* h0 = (unsigned short*)(ws + off); off += (size_t)B_DIM * H_DIM * 2;
    unsigned short* h1 = (unsigned short*)(ws + off); off += (size_t)B_DIM * H_DIM * 2;
    float* c           = (float*)(ws + off);          off += (size_t)B_DIM * H_DIM * 4;
    float* wT          = (float*)(ws + off);          off += (size_t)H_DIM * O_DIM * 4;

    conv_x<<<8192, 256, 0, stream>>>(x, xb);
    build_w<<<GDIM, 256, 0, stream>>>(w_ih, w_hh, b_ih, b_hh, W, bias);
    trans_wfc<<<O_DIM, 256, 0, stream>>>(w_fc, wT);
    zero_hc<<<4096, 256, 0, stream>>>(h0, c);

    for (int t = 0; t < T_DIM; ++t) {
        const unsigned short* hin = (t & 1) ? h1 : h0;
        unsigned short* hout      = (t & 1) ? h0 : h1;
        lstm_step<<<256, 512, 0, stream>>>(xb, W, bias, hin, hout, c, t);
    }
    // t=127 wrote h0
    proj<<<256, 256, 0, stream>>>(h0, wT, b_fc, out);
}